// Round 1
// baseline (3994.445 us; speedup 1.0000x reference)
//
#include <hip/hip_runtime.h>
#include <math.h>

#define B_  16
#define C_  192
#define N_  3136
#define BN_ 50176
#define K_  9
#define NC_ 100
#define PD_ 1024

#define OUT_EATT 1600
#define OUT_PP   453184

// ---------------- normalize: [B,C,N] -> xn [B*N, C] (L2 rows) ----------------
__global__ __launch_bounds__(256) void k_normalize(const float* __restrict__ in,
                                                   float* __restrict__ xn) {
    __shared__ float tile[C_][65];
    __shared__ float part[4][64];
    __shared__ float rnorm[64];
    int blk = blockIdx.x;
    int b = blk / 49;
    int n0 = (blk % 49) * 64;
    int t = threadIdx.x;
    for (int f = t; f < C_ * 64; f += 256) {
        int c = f >> 6, n = f & 63;
        tile[c][n] = in[((size_t)b * C_ + c) * N_ + n0 + n];
    }
    __syncthreads();
    {
        int n = t & 63, qq = t >> 6;
        float s = 0.f;
        #pragma unroll
        for (int i = 0; i < 48; ++i) { float v = tile[qq * 48 + i][n]; s += v * v; }
        part[qq][n] = s;
    }
    __syncthreads();
    if (t < 64) {
        float tot = part[0][t] + part[1][t] + part[2][t] + part[3][t];
        rnorm[t] = 1.0f / fmaxf(sqrtf(tot), 1e-12f);
    }
    __syncthreads();
    for (int f = t; f < 64 * C_; f += 256) {
        int n = f / C_, c = f - n * C_;
        xn[((size_t)(b * N_ + n0 + n)) * C_ + c] = tile[c][n] * rnorm[n];
    }
}

// ---------------- patch prediction: 1x1 conv ----------------
__global__ __launch_bounds__(256) void k_patch(const float* __restrict__ in,
        const float* __restrict__ cw, const float* __restrict__ cb,
        float* __restrict__ outp) {
    int tid = blockIdx.x * 256 + threadIdx.x;     // 313600 threads
    int n4 = tid % 784;
    int k4 = (tid / 784) % 25;
    int b  = tid / 19600;
    const float* xb = in + (size_t)b * C_ * N_ + n4 * 4;
    const float* wb = cw + (size_t)k4 * 4 * C_;
    float4 a0 = {0,0,0,0}, a1 = {0,0,0,0}, a2 = {0,0,0,0}, a3 = {0,0,0,0};
    for (int c = 0; c < C_; ++c) {
        float4 x = *(const float4*)(xb + (size_t)c * N_);
        float w0 = wb[c], w1 = wb[C_ + c], w2 = wb[2 * C_ + c], w3 = wb[3 * C_ + c];
        a0.x += x.x*w0; a0.y += x.y*w0; a0.z += x.z*w0; a0.w += x.w*w0;
        a1.x += x.x*w1; a1.y += x.y*w1; a1.z += x.z*w1; a1.w += x.w*w1;
        a2.x += x.x*w2; a2.y += x.y*w2; a2.z += x.z*w2; a2.w += x.w*w2;
        a3.x += x.x*w3; a3.y += x.y*w3; a3.z += x.z*w3; a3.w += x.w*w3;
    }
    float b0 = cb[k4*4+0], b1 = cb[k4*4+1], b2 = cb[k4*4+2], b3 = cb[k4*4+3];
    float4 r;
    r = make_float4(a0.x+b0, a0.y+b0, a0.z+b0, a0.w+b0);
    *(float4*)(outp + ((size_t)(b*NC_ + k4*4+0))*N_ + n4*4) = r;
    r = make_float4(a1.x+b1, a1.y+b1, a1.z+b1, a1.w+b1);
    *(float4*)(outp + ((size_t)(b*NC_ + k4*4+1))*N_ + n4*4) = r;
    r = make_float4(a2.x+b2, a2.y+b2, a2.z+b2, a2.w+b2);
    *(float4*)(outp + ((size_t)(b*NC_ + k4*4+2))*N_ + n4*4) = r;
    r = make_float4(a3.x+b3, a3.y+b3, a3.z+b3, a3.w+b3);
    *(float4*)(outp + ((size_t)(b*NC_ + k4*4+3))*N_ + n4*4) = r;
}

// compare-exchange insertion step (sorted desc list, stable on ties via scan order)
#define CX(TV,TI) { bool p = (v > TV); float f_ = p ? TV : v; int i_ = p ? TI : vi; \
                    TV = p ? v : TV; TI = p ? vi : TI; v = f_; vi = i_; }
// tie-aware (val desc, idx asc) for the merge
#define CXT(TV,TI) { bool p = (v > TV) || (v == TV && vi < TI); \
                     float f_ = p ? TV : v; int i_ = p ? TI : vi; \
                     TV = p ? v : TV; TI = p ? vi : TI; v = f_; vi = i_; }

#define DOT3(A, J0) { float4 x4, c4; \
  x4 = xr[J0+0]; c4 = cp[J0+0]; A += x4.x*c4.x; A += x4.y*c4.y; A += x4.z*c4.z; A += x4.w*c4.w; \
  x4 = xr[J0+1]; c4 = cp[J0+1]; A += x4.x*c4.x; A += x4.y*c4.y; A += x4.z*c4.z; A += x4.w*c4.w; \
  x4 = xr[J0+2]; c4 = cp[J0+2]; A += x4.x*c4.x; A += x4.y*c4.y; A += x4.z*c4.z; A += x4.w*c4.w; }

// ---------------- fused sim + top-9 (per image, per column-quarter) ----------------
// grid: B * 49 rowtiles * 4 quarters = 3136 blocks, 256 threads.
// 4 threads (quad) per row; each holds 48 of 192 row elems in regs.
__global__ __launch_bounds__(256) void k_simtopk(const float* __restrict__ xn,
        float* __restrict__ topv, int* __restrict__ topi) {
    __shared__ float4 colbuf[49 * 48];             // 49 cols x 192 c
    int blk = blockIdx.x;
    int b   = blk / 196;
    int rem = blk % 196;
    int rt  = rem >> 2;
    int cq  = rem & 3;
    int r0  = rt * 64;
    int t = threadIdx.x;
    int q = t & 3;
    int r = r0 + (t >> 2);
    const float* rowp = xn + ((size_t)b * N_ + r) * C_ + q * 48;
    float4 xr[12];
    #pragma unroll
    for (int j = 0; j < 12; ++j) xr[j] = *(const float4*)(rowp + 4 * j);
    float tv0=-1e30f,tv1=-1e30f,tv2=-1e30f,tv3=-1e30f,tv4=-1e30f,
          tv5=-1e30f,tv6=-1e30f,tv7=-1e30f,tv8=-1e30f;
    int   ti0=0,ti1=0,ti2=0,ti3=0,ti4=0,ti5=0,ti6=0,ti7=0,ti8=0;
    const float4* xb4 = (const float4*)(xn + (size_t)b * N_ * C_);
    for (int tile = 0; tile < 16; ++tile) {
        int c0 = cq * 784 + tile * 49;
        __syncthreads();
        for (int f = t; f < 49 * 48; f += 256)
            colbuf[f] = xb4[(size_t)c0 * 48 + f];
        __syncthreads();
        for (int cc = 0; cc < 49; ++cc) {
            const float4* cp = colbuf + cc * 48 + q * 12;
            float a0 = 0.f, a1 = 0.f, a2 = 0.f, a3 = 0.f;
            DOT3(a0, 0) DOT3(a1, 3) DOT3(a2, 6) DOT3(a3, 9)
            float v = (a0 + a1) + (a2 + a3);
            v += __shfl_xor(v, 1, 64);
            v += __shfl_xor(v, 2, 64);
            int cg = c0 + cc;
            int vi = cg;
            if (cg == r) v = -1e30f;               // exclude self (sim - 4*eye)
            if (v > tv8) { CX(tv0,ti0) CX(tv1,ti1) CX(tv2,ti2) CX(tv3,ti3)
                           CX(tv4,ti4) CX(tv5,ti5) CX(tv6,ti6) CX(tv7,ti7) CX(tv8,ti8) }
        }
    }
    if (q == 0) {
        size_t base = ((size_t)cq * BN_ + (size_t)b * N_ + r) * K_;
        int gb = b * N_;
        topv[base+0]=tv0; topi[base+0]=gb+ti0;
        topv[base+1]=tv1; topi[base+1]=gb+ti1;
        topv[base+2]=tv2; topi[base+2]=gb+ti2;
        topv[base+3]=tv3; topi[base+3]=gb+ti3;
        topv[base+4]=tv4; topi[base+4]=gb+ti4;
        topv[base+5]=tv5; topi[base+5]=gb+ti5;
        topv[base+6]=tv6; topi[base+6]=gb+ti6;
        topv[base+7]=tv7; topi[base+7]=gb+ti7;
        topv[base+8]=tv8; topi[base+8]=gb+ti8;
    }
}

// ---------------- merge the 4 per-quarter top-9 lists -> final neighbors ----------------
__global__ __launch_bounds__(256) void k_merge(const float* __restrict__ topv,
        const int* __restrict__ topi, int* __restrict__ nbr) {
    int row = blockIdx.x * 256 + threadIdx.x;      // 196*256 = 50176
    float tv0=-1e30f,tv1=-1e30f,tv2=-1e30f,tv3=-1e30f,tv4=-1e30f,
          tv5=-1e30f,tv6=-1e30f,tv7=-1e30f,tv8=-1e30f;
    int   ti0=0x7fffffff,ti1=0x7fffffff,ti2=0x7fffffff,ti3=0x7fffffff,ti4=0x7fffffff,
          ti5=0x7fffffff,ti6=0x7fffffff,ti7=0x7fffffff,ti8=0x7fffffff;
    #pragma unroll
    for (int qq = 0; qq < 4; ++qq) {
        size_t base = ((size_t)qq * BN_ + row) * K_;
        #pragma unroll
        for (int k = 0; k < K_; ++k) {
            float v = topv[base + k];
            int  vi = topi[base + k];
            bool enter = (v > tv8) || (v == tv8 && vi < ti8);
            if (enter) { CXT(tv0,ti0) CXT(tv1,ti1) CXT(tv2,ti2) CXT(tv3,ti3)
                         CXT(tv4,ti4) CXT(tv5,ti5) CXT(tv6,ti6) CXT(tv7,ti7) CXT(tv8,ti8) }
        }
    }
    int* np_ = nbr + (size_t)row * K_;
    np_[0]=ti0; np_[1]=ti1; np_[2]=ti2; np_[3]=ti3; np_[4]=ti4;
    np_[5]=ti5; np_[6]=ti6; np_[7]=ti7; np_[8]=ti8;
}

// ---------------- GNN linear + relu: h = relu(xn @ W + b) ----------------
// grid 1568 blocks x 192 threads; 32 nodes/block
__global__ __launch_bounds__(192) void k_gnn(const float* __restrict__ xn,
        const float* __restrict__ w, const float* __restrict__ bias,
        float* __restrict__ h) {
    __shared__ float4 xs[32 * 48];
    int nb = blockIdx.x * 32;
    int t = threadIdx.x;                           // output channel
    const float4* xp = (const float4*)(xn + (size_t)nb * C_);
    #pragma unroll
    for (int i = 0; i < 8; ++i) xs[t + i * 192] = xp[t + i * 192];
    __syncthreads();
    float acc[32];
    #pragma unroll
    for (int i = 0; i < 32; ++i) acc[i] = 0.f;
    for (int c0 = 0; c0 < C_; c0 += 32) {
        float wr[32];
        #pragma unroll
        for (int i = 0; i < 32; ++i) wr[i] = w[(size_t)(c0 + i) * C_ + t];
        #pragma unroll
        for (int nd = 0; nd < 32; ++nd) {
            #pragma unroll
            for (int ii = 0; ii < 8; ++ii) {
                float4 xv = xs[nd * 48 + (c0 >> 2) + ii];
                acc[nd] += xv.x * wr[ii*4+0] + xv.y * wr[ii*4+1]
                         + xv.z * wr[ii*4+2] + xv.w * wr[ii*4+3];
            }
        }
    }
    float bv = bias[t];
    #pragma unroll
    for (int nd = 0; nd < 32; ++nd)
        h[((size_t)nb + nd) * C_ + t] = fmaxf(acc[nd] + bv, 0.f);
}

// ---------------- edge attention + neighbor mean aggregation ----------------
// one wave per node; 4 nodes per 256-thread block
__global__ __launch_bounds__(256) void k_edge(const float* __restrict__ h,
        const int* __restrict__ nbr, float* __restrict__ eatt,
        float* __restrict__ hout) {
    int node = blockIdx.x * 4 + (threadIdx.x >> 6);
    int lane = threadIdx.x & 63;
    const float* hc = h + (size_t)node * C_;
    float c0 = hc[lane], c1 = hc[lane + 64], c2 = hc[lane + 128];
    float m0 = 0.f, m1 = 0.f, m2 = 0.f;
    const int* np_ = nbr + (size_t)node * K_;
    float* ep = eatt + (size_t)node * K_;
    #pragma unroll
    for (int k = 0; k < K_; ++k) {
        int src = np_[k];
        const float* hs = h + (size_t)src * C_;
        float s0 = hs[lane], s1 = hs[lane + 64], s2 = hs[lane + 128];
        float d = c0 * s0 + c1 * s1 + c2 * s2;
        d += __shfl_xor(d, 1, 64);  d += __shfl_xor(d, 2, 64);
        d += __shfl_xor(d, 4, 64);  d += __shfl_xor(d, 8, 64);
        d += __shfl_xor(d, 16, 64); d += __shfl_xor(d, 32, 64);
        if (lane == 0) ep[k] = 1.0f / (1.0f + expf(-d));
        m0 += s0; m1 += s1; m2 += s2;
    }
    const float r9 = 1.0f / 9.0f;
    float* ho = hout + (size_t)node * C_;
    ho[lane]       = c0 + m0 * r9;
    ho[lane + 64]  = c1 + m1 * r9;
    ho[lane + 128] = c2 + m2 * r9;
}

// ---------------- global add pool (partial, deterministic) ----------------
__global__ __launch_bounds__(192) void k_gred(const float* __restrict__ hout,
        float* __restrict__ gpart) {
    int b = blockIdx.x >> 3, s = blockIdx.x & 7;
    int oc = threadIdx.x;
    float acc = 0.f;
    for (int n = s * 392; n < (s + 1) * 392; ++n)
        acc += hout[((size_t)b * N_ + n) * C_ + oc];
    gpart[(size_t)blockIdx.x * C_ + oc] = acc;
}

// ---------------- MLP head: Linear -> BN(train) -> GELU -> Linear ----------------
__global__ __launch_bounds__(1024) void k_mlp(const float* __restrict__ gpart,
        const float* __restrict__ w1, const float* __restrict__ b1,
        const float* __restrict__ gam, const float* __restrict__ bet,
        const float* __restrict__ w2, const float* __restrict__ b2,
        float* __restrict__ pred) {
    __shared__ float gs[B_ * C_];
    __shared__ float zs[B_ * PD_];
    int t = threadIdx.x;
    for (int f = t; f < B_ * C_; f += 1024) {
        int b = f / C_, oc = f - b * C_;
        float a = 0.f;
        for (int s = 0; s < 8; ++s) a += gpart[((size_t)b * 8 + s) * C_ + oc];
        gs[f] = a;
    }
    __syncthreads();
    int j = t;
    float z[16];
    #pragma unroll
    for (int i = 0; i < 16; ++i) z[i] = b1[j];
    for (int c = 0; c < C_; ++c) {
        float w = w1[(size_t)c * PD_ + j];
        #pragma unroll
        for (int i = 0; i < 16; ++i) z[i] += gs[i * C_ + c] * w;
    }
    float mu = 0.f;
    #pragma unroll
    for (int i = 0; i < 16; ++i) mu += z[i];
    mu *= (1.0f / 16.0f);
    float var = 0.f;
    #pragma unroll
    for (int i = 0; i < 16; ++i) { float d = z[i] - mu; var += d * d; }
    var *= (1.0f / 16.0f);
    float sc = (1.0f / sqrtf(var + 1e-5f)) * gam[j];
    float bt = bet[j];
    #pragma unroll
    for (int i = 0; i < 16; ++i) {
        float zh = (z[i] - mu) * sc + bt;
        float ge = 0.5f * zh * (1.0f + erff(zh * 0.70710678118654752f));
        zs[i * PD_ + j] = ge;
    }
    __syncthreads();
    for (int idx = t; idx < B_ * NC_; idx += 1024) {
        int i = idx / NC_, jj = idx - i * NC_;
        float a = b2[jj];
        for (int k = 0; k < PD_; ++k) a += zs[i * PD_ + k] * w2[(size_t)k * NC_ + jj];
        pred[idx] = a;
    }
}

extern "C" void kernel_launch(void* const* d_in, const int* in_sizes, int n_in,
                              void* d_out, int out_size, void* d_ws, size_t ws_size,
                              hipStream_t stream) {
    const float* img    = (const float*)d_in[0];
    const float* conv_w = (const float*)d_in[1];
    const float* conv_b = (const float*)d_in[2];
    const float* gnn_w  = (const float*)d_in[3];
    const float* gnn_b  = (const float*)d_in[4];
    const float* w1     = (const float*)d_in[5];
    const float* b1     = (const float*)d_in[6];
    const float* bng    = (const float*)d_in[7];
    const float* bnb    = (const float*)d_in[8];
    const float* w2     = (const float*)d_in[9];
    const float* b2     = (const float*)d_in[10];
    float* out = (float*)d_out;

    float* XN   = (float*)d_ws;                       // BN_*C_  (reused as HOUT later)
    float* TOPV = XN + (size_t)BN_ * C_;              // 4*BN_*K_
    int*   TOPI = (int*)(TOPV + (size_t)4 * BN_ * K_);// 4*BN_*K_
    int*   NBR  = TOPI + (size_t)4 * BN_ * K_;        // BN_*K_
    float* Hh   = (float*)(NBR + (size_t)BN_ * K_);   // BN_*C_
    float* HOUT = XN;                                  // reuse (xn dead after k_gnn)
    float* GPART= Hh + (size_t)BN_ * C_;              // 16*8*C_

    k_normalize<<<784, 256, 0, stream>>>(img, XN);
    k_patch   <<<1225, 256, 0, stream>>>(img, conv_w, conv_b, out + OUT_PP);
    k_simtopk <<<3136, 256, 0, stream>>>(XN, TOPV, TOPI);
    k_merge   <<<196, 256, 0, stream>>>(TOPV, TOPI, NBR);
    k_gnn     <<<1568, 192, 0, stream>>>(XN, gnn_w, gnn_b, Hh);
    k_edge    <<<12544, 256, 0, stream>>>(Hh, NBR, out + OUT_EATT, HOUT);
    k_gred    <<<128, 192, 0, stream>>>(HOUT, GPART);
    k_mlp     <<<1, 1024, 0, stream>>>(GPART, w1, b1, bng, bnb, w2, b2, out);
}

// Round 2
// 1411.589 us; speedup vs baseline: 2.8298x; 2.8298x over previous
//
#include <hip/hip_runtime.h>
#include <math.h>

#define B_  16
#define C_  192
#define N_  3136
#define BN_ 50176
#define K_  9
#define NC_ 100
#define PD_ 1024

#define OUT_EATT 1600
#define OUT_PP   453184

typedef short bf16x8 __attribute__((ext_vector_type(8)));
typedef float f32x4  __attribute__((ext_vector_type(4)));

#define SIM_LDS 132096   // 2*48KB B double-buffer + 64*132*4 scan buffer

// sorted-desc insertion, strict > (stable: earliest inserted wins ties)
template<int NL>
__device__ inline void ins_gt(float (&lv)[NL], int (&li)[NL], float v, int vi) {
    if (v > lv[NL-1]) {
        #pragma unroll
        for (int k = 0; k < NL; ++k) {
            bool p = v > lv[k];
            float fv = p ? lv[k] : v; int fi = p ? li[k] : vi;
            lv[k] = p ? v : lv[k];    li[k] = p ? vi : li[k];
            v = fv; vi = fi;
        }
    }
}
// lexicographic (val desc, idx asc) insertion for merges
template<int NL>
__device__ inline void ins_lex(float (&lv)[NL], int (&li)[NL], float v, int vi) {
    if (v > lv[NL-1] || (v == lv[NL-1] && vi < li[NL-1])) {
        #pragma unroll
        for (int k = 0; k < NL; ++k) {
            bool p = (v > lv[k]) || (v == lv[k] && vi < li[k]);
            float fv = p ? lv[k] : v; int fi = p ? li[k] : vi;
            lv[k] = p ? v : lv[k];    li[k] = p ? vi : li[k];
            v = fv; vi = fi;
        }
    }
}

// ---------------- normalize: [B,C,N] -> xn [B*N, C] (L2 rows) ----------------
__global__ __launch_bounds__(256) void k_normalize(const float* __restrict__ in,
                                                   float* __restrict__ xn) {
    __shared__ float tile[C_][65];
    __shared__ float part[4][64];
    __shared__ float rnorm[64];
    int blk = blockIdx.x;
    int b = blk / 49;
    int n0 = (blk % 49) * 64;
    int t = threadIdx.x;
    for (int f = t; f < C_ * 64; f += 256) {
        int c = f >> 6, n = f & 63;
        tile[c][n] = in[((size_t)b * C_ + c) * N_ + n0 + n];
    }
    __syncthreads();
    {
        int n = t & 63, qq = t >> 6;
        float s = 0.f;
        #pragma unroll
        for (int i = 0; i < 48; ++i) { float v = tile[qq * 48 + i][n]; s += v * v; }
        part[qq][n] = s;
    }
    __syncthreads();
    if (t < 64) {
        float tot = part[0][t] + part[1][t] + part[2][t] + part[3][t];
        rnorm[t] = 1.0f / fmaxf(sqrtf(tot), 1e-12f);
    }
    __syncthreads();
    for (int f = t; f < 64 * C_; f += 256) {
        int n = f / C_, c = f - n * C_;
        xn[((size_t)(b * N_ + n0 + n)) * C_ + c] = tile[c][n] * rnorm[n];
    }
}

// ---------------- patch prediction: 1x1 conv ----------------
__global__ __launch_bounds__(256) void k_patch(const float* __restrict__ in,
        const float* __restrict__ cw, const float* __restrict__ cb,
        float* __restrict__ outp) {
    int tid = blockIdx.x * 256 + threadIdx.x;
    int n4 = tid % 784;
    int k4 = (tid / 784) % 25;
    int b  = tid / 19600;
    const float* xb = in + (size_t)b * C_ * N_ + n4 * 4;
    const float* wb = cw + (size_t)k4 * 4 * C_;
    float4 a0 = {0,0,0,0}, a1 = {0,0,0,0}, a2 = {0,0,0,0}, a3 = {0,0,0,0};
    for (int c = 0; c < C_; ++c) {
        float4 x = *(const float4*)(xb + (size_t)c * N_);
        float w0 = wb[c], w1 = wb[C_ + c], w2 = wb[2 * C_ + c], w3 = wb[3 * C_ + c];
        a0.x += x.x*w0; a0.y += x.y*w0; a0.z += x.z*w0; a0.w += x.w*w0;
        a1.x += x.x*w1; a1.y += x.y*w1; a1.z += x.z*w1; a1.w += x.w*w1;
        a2.x += x.x*w2; a2.y += x.y*w2; a2.z += x.z*w2; a2.w += x.w*w2;
        a3.x += x.x*w3; a3.y += x.y*w3; a3.z += x.z*w3; a3.w += x.w*w3;
    }
    float b0 = cb[k4*4+0], b1 = cb[k4*4+1], b2 = cb[k4*4+2], b3 = cb[k4*4+3];
    float4 r;
    r = make_float4(a0.x+b0, a0.y+b0, a0.z+b0, a0.w+b0);
    *(float4*)(outp + ((size_t)(b*NC_ + k4*4+0))*N_ + n4*4) = r;
    r = make_float4(a1.x+b1, a1.y+b1, a1.z+b1, a1.w+b1);
    *(float4*)(outp + ((size_t)(b*NC_ + k4*4+1))*N_ + n4*4) = r;
    r = make_float4(a2.x+b2, a2.y+b2, a2.z+b2, a2.w+b2);
    *(float4*)(outp + ((size_t)(b*NC_ + k4*4+2))*N_ + n4*4) = r;
    r = make_float4(a3.x+b3, a3.y+b3, a3.z+b3, a3.w+b3);
    *(float4*)(outp + ((size_t)(b*NC_ + k4*4+3))*N_ + n4*4) = r;
}

// ---------------- split fp32 -> (hi|lo) bf16, row layout [384] ----------------
__device__ inline unsigned int bf16_rne(unsigned int u) {
    return (u + 0x7fffu + ((u >> 16) & 1u)) & 0xffff0000u;
}
__global__ __launch_bounds__(256) void k_split(const float* __restrict__ xn,
        unsigned short* __restrict__ xs) {
    int tid = blockIdx.x * 256 + threadIdx.x;      // BN*48 = 2408448
    int row = tid / 48, c4 = tid - row * 48;
    float4 x = *(const float4*)(xn + (size_t)row * 192 + c4 * 4);
    float xv[4] = {x.x, x.y, x.z, x.w};
    unsigned short hi[4], lo[4];
    #pragma unroll
    for (int c = 0; c < 4; ++c) {
        unsigned int u = __float_as_uint(xv[c]);
        unsigned int r = bf16_rne(u);
        hi[c] = (unsigned short)(r >> 16);
        float l = xv[c] - __uint_as_float(r);
        lo[c] = (unsigned short)(bf16_rne(__float_as_uint(l)) >> 16);
    }
    unsigned short* rp = xs + (size_t)row * 384 + c4 * 4;
    *(ushort4*)(rp)       = make_ushort4(hi[0], hi[1], hi[2], hi[3]);
    *(ushort4*)(rp + 192) = make_ushort4(lo[0], lo[1], lo[2], lo[3]);
}

// ---------------- MFMA sim + fused top-12 ----------------
// grid 800: bid = (half*25 + rblk)*16 + img. 256 thr = 4 waves (2x2), wave 64r x 32c.
// A (64 rows x K384) resident in regs; B 64-col chunks staged via global_load_lds.
__global__ __launch_bounds__(256, 1) void k_simmfma(const unsigned short* __restrict__ xs,
        float* __restrict__ topv, int* __restrict__ topi) {
    extern __shared__ char SM[];
    float* scanb = (float*)(SM + 98304);
    int bid = blockIdx.x;
    int img = bid & 15;
    int sub = bid >> 4;
    int rblk = sub % 25;
    int half = sub / 25;
    int t = threadIdx.x;
    int w = t >> 6, lane = t & 63;
    int wr = w >> 1, wc = w & 1;
    int l15 = lane & 15, lk = lane >> 4;
    const unsigned short* xsi = xs + (size_t)img * N_ * 384;

    // A fragments: rowtile i, kstep s
    bf16x8 a[4][12];
    int rbase = rblk * 128 + wr * 64;
    #pragma unroll
    for (int i = 0; i < 4; ++i) {
        int r = rbase + i * 16 + l15;
        if (r > N_ - 1) r = N_ - 1;
        const unsigned short* rp = xsi + (size_t)r * 384 + lk * 8;
        #pragma unroll
        for (int s = 0; s < 12; ++s)
            a[i][s] = *(const bf16x8*)(rp + s * 32);
    }

    // scan state: thread pair per row (col halves)
    int srow = t >> 1, sch = t & 1;
    int rig = rblk * 128 + srow;
    bool valid = rig < N_;
    float lv[12]; int li[12];
    #pragma unroll
    for (int k = 0; k < 12; ++k) { lv[k] = -1e30f; li[k] = 0; }

    int nch = half ? 24 : 25;
    int cb0 = half ? 1600 : 0;

    // prologue: stage chunk 0 into buf 0
    {
        const unsigned short* src0 = xsi + (size_t)(cb0 + lane) * 384;
        #pragma unroll
        for (int q = 0; q < 12; ++q) {
            int sg = w * 12 + q;
            __builtin_amdgcn_global_load_lds(
                (const __attribute__((address_space(1))) unsigned int*)(src0 + (sg >> 2) * 32 + (sg & 3) * 8),
                (__attribute__((address_space(3))) unsigned int*)(SM + sg * 1024), 16, 0, 0);
        }
    }
    __syncthreads();

    for (int c = 0; c < nch; ++c) {
        int bsel = c & 1;
        if (c + 1 < nch) {   // stage next chunk into other buffer
            const unsigned short* src0 = xsi + (size_t)(cb0 + (c + 1) * 64 + lane) * 384;
            char* dstb = SM + (bsel ^ 1) * 49152;
            #pragma unroll
            for (int q = 0; q < 12; ++q) {
                int sg = w * 12 + q;
                __builtin_amdgcn_global_load_lds(
                    (const __attribute__((address_space(1))) unsigned int*)(src0 + (sg >> 2) * 32 + (sg & 3) * 8),
                    (__attribute__((address_space(3))) unsigned int*)(dstb + sg * 1024), 16, 0, 0);
            }
        }
        // compute 64x64 block sim tile (this wave: 64r x 32c)
        const char* bp = SM + bsel * 49152 + wc * 512 + lk * 1024 + l15 * 16;
        f32x4 acc[4][2];
        #pragma unroll
        for (int i = 0; i < 4; ++i) { acc[i][0] = (f32x4){0,0,0,0}; acc[i][1] = (f32x4){0,0,0,0}; }
        #pragma unroll
        for (int s = 0; s < 12; ++s) {
            bf16x8 b0 = *(const bf16x8*)(bp + s * 4096);
            bf16x8 b1 = *(const bf16x8*)(bp + s * 4096 + 256);
            #pragma unroll
            for (int i = 0; i < 4; ++i) {
                acc[i][0] = __builtin_amdgcn_mfma_f32_16x16x32_bf16(a[i][s], b0, acc[i][0], 0, 0, 0);
                acc[i][1] = __builtin_amdgcn_mfma_f32_16x16x32_bf16(a[i][s], b1, acc[i][1], 0, 0, 0);
            }
        }
        // acc -> scan buffer (col-major, stride 132 words)
        #pragma unroll
        for (int i = 0; i < 4; ++i) {
            int row0 = wr * 64 + i * 16 + lk * 4;
            #pragma unroll
            for (int j = 0; j < 2; ++j) {
                int col = wc * 32 + j * 16 + l15;
                *(f32x4*)(scanb + col * 132 + row0) = acc[i][j];
            }
        }
        __syncthreads();
        // per-row top-12 scan (2 threads/row, 32 cols each)
        if (valid) {
            int cgbase = cb0 + c * 64 + sch * 32;
            const float* sp = scanb + sch * 32 * 132 + srow;
            #pragma unroll 4
            for (int cc = 0; cc < 32; ++cc) {
                float v = sp[cc * 132];
                int vi = cgbase + cc;
                if (vi != rig) ins_gt<12>(lv, li, v, vi);
            }
        }
        __syncthreads();
    }
    // merge the col-half partner's list (shfl across lane pair)
    float mv[12]; int mi[12];
    #pragma unroll
    for (int k = 0; k < 12; ++k) {
        mv[k] = __shfl_xor(lv[k], 1, 64);
        mi[k] = __shfl_xor(li[k], 1, 64);
    }
    #pragma unroll
    for (int k = 0; k < 12; ++k) ins_lex<12>(lv, li, mv[k], mi[k]);
    if (valid && sch == 0) {
        size_t base = ((size_t)half * BN_ + (size_t)img * N_ + rig) * 12;
        #pragma unroll
        for (int k = 0; k < 12; ++k) { topv[base + k] = lv[k]; topi[base + k] = li[k]; }
    }
}

// ---------------- merge 2 col-half partials -> top-12 candidates ----------------
__global__ __launch_bounds__(256) void k_merge2(const float* __restrict__ topv,
        const int* __restrict__ topi, int* __restrict__ nbr12) {
    int row = blockIdx.x * 256 + threadIdx.x;      // 50176
    float lv[12]; int li[12];
    #pragma unroll
    for (int k = 0; k < 12; ++k) { lv[k] = -1e30f; li[k] = 0x7fffffff; }
    #pragma unroll
    for (int h = 0; h < 2; ++h) {
        size_t base = ((size_t)h * BN_ + row) * 12;
        #pragma unroll
        for (int k = 0; k < 12; ++k)
            ins_lex<12>(lv, li, topv[base + k], topi[base + k]);
    }
    int gb = (row / N_) * N_;
    int* np = nbr12 + (size_t)row * 12;
    #pragma unroll
    for (int k = 0; k < 12; ++k) np[k] = gb + li[k];
}

// ---------------- exact fp32 rescore of 12 candidates -> final top-9 ----------------
// 16 lanes per row, 4 rows per wave. grid 3136 x 256.
__global__ __launch_bounds__(256) void k_rescore(const float* __restrict__ xn,
        const int* __restrict__ nbr12, int* __restrict__ nbr9) {
    int gid = blockIdx.x * 256 + threadIdx.x;
    int lane = threadIdx.x & 63;
    int row = (gid >> 6) * 4 + (lane >> 4);        // 0..50175
    int c = lane & 15;
    int cand = nbr12[(size_t)row * 12 + (c < 12 ? c : 0)];
    const float4* xa = (const float4*)(xn + (size_t)row * C_);
    const float4* xb = (const float4*)(xn + (size_t)cand * C_);
    float dot = 0.f;
    #pragma unroll
    for (int k = 0; k < 48; ++k) {
        float4 p = xa[k], q = xb[k];
        dot += p.x*q.x + p.y*q.y + p.z*q.z + p.w*q.w;
    }
    float v = (c < 12 && cand != row) ? dot : -1e30f;
    float lv[9]; int li[9];
    #pragma unroll
    for (int k = 0; k < 9; ++k) { lv[k] = -1e30f; li[k] = 0x7fffffff; }
    int gbase = lane & 48;
    #pragma unroll
    for (int j = 0; j < 12; ++j) {
        float vj = __shfl(v, gbase + j, 64);
        int  ij = __shfl(cand, gbase + j, 64);
        ins_lex<9>(lv, li, vj, ij);
    }
    if (c == 0) {
        int* np = nbr9 + (size_t)row * 9;
        #pragma unroll
        for (int k = 0; k < 9; ++k) np[k] = li[k];
    }
}

// ---------------- GNN linear + relu ----------------
__global__ __launch_bounds__(192) void k_gnn(const float* __restrict__ xn,
        const float* __restrict__ w, const float* __restrict__ bias,
        float* __restrict__ h) {
    __shared__ float4 xs[32 * 48];
    int nb = blockIdx.x * 32;
    int t = threadIdx.x;
    const float4* xp = (const float4*)(xn + (size_t)nb * C_);
    #pragma unroll
    for (int i = 0; i < 8; ++i) xs[t + i * 192] = xp[t + i * 192];
    __syncthreads();
    float acc[32];
    #pragma unroll
    for (int i = 0; i < 32; ++i) acc[i] = 0.f;
    for (int c0 = 0; c0 < C_; c0 += 32) {
        float wr[32];
        #pragma unroll
        for (int i = 0; i < 32; ++i) wr[i] = w[(size_t)(c0 + i) * C_ + t];
        #pragma unroll
        for (int nd = 0; nd < 32; ++nd) {
            #pragma unroll
            for (int ii = 0; ii < 8; ++ii) {
                float4 xv = xs[nd * 48 + (c0 >> 2) + ii];
                acc[nd] += xv.x * wr[ii*4+0] + xv.y * wr[ii*4+1]
                         + xv.z * wr[ii*4+2] + xv.w * wr[ii*4+3];
            }
        }
    }
    float bv = bias[t];
    #pragma unroll
    for (int nd = 0; nd < 32; ++nd)
        h[((size_t)nb + nd) * C_ + t] = fmaxf(acc[nd] + bv, 0.f);
}

// ---------------- edge attention + neighbor mean aggregation ----------------
__global__ __launch_bounds__(256) void k_edge(const float* __restrict__ h,
        const int* __restrict__ nbr, float* __restrict__ eatt,
        float* __restrict__ hout) {
    int node = blockIdx.x * 4 + (threadIdx.x >> 6);
    int lane = threadIdx.x & 63;
    const float* hc = h + (size_t)node * C_;
    float c0 = hc[lane], c1 = hc[lane + 64], c2 = hc[lane + 128];
    float m0 = 0.f, m1 = 0.f, m2 = 0.f;
    const int* np_ = nbr + (size_t)node * K_;
    float* ep = eatt + (size_t)node * K_;
    #pragma unroll
    for (int k = 0; k < K_; ++k) {
        int src = np_[k];
        const float* hs = h + (size_t)src * C_;
        float s0 = hs[lane], s1 = hs[lane + 64], s2 = hs[lane + 128];
        float d = c0 * s0 + c1 * s1 + c2 * s2;
        d += __shfl_xor(d, 1, 64);  d += __shfl_xor(d, 2, 64);
        d += __shfl_xor(d, 4, 64);  d += __shfl_xor(d, 8, 64);
        d += __shfl_xor(d, 16, 64); d += __shfl_xor(d, 32, 64);
        if (lane == 0) ep[k] = 1.0f / (1.0f + expf(-d));
        m0 += s0; m1 += s1; m2 += s2;
    }
    const float r9 = 1.0f / 9.0f;
    float* ho = hout + (size_t)node * C_;
    ho[lane]       = c0 + m0 * r9;
    ho[lane + 64]  = c1 + m1 * r9;
    ho[lane + 128] = c2 + m2 * r9;
}

// ---------------- global add pool (partial) ----------------
__global__ __launch_bounds__(192) void k_gred(const float* __restrict__ hout,
        float* __restrict__ gpart) {
    int b = blockIdx.x >> 3, s = blockIdx.x & 7;
    int oc = threadIdx.x;
    float acc = 0.f;
    for (int n = s * 392; n < (s + 1) * 392; ++n)
        acc += hout[((size_t)b * N_ + n) * C_ + oc];
    gpart[(size_t)blockIdx.x * C_ + oc] = acc;
}

// ---------------- MLP head ----------------
__global__ __launch_bounds__(1024) void k_mlp(const float* __restrict__ gpart,
        const float* __restrict__ w1, const float* __restrict__ b1,
        const float* __restrict__ gam, const float* __restrict__ bet,
        const float* __restrict__ w2, const float* __restrict__ b2,
        float* __restrict__ pred) {
    __shared__ float gs[B_ * C_];
    __shared__ float zs[B_ * PD_];
    int t = threadIdx.x;
    for (int f = t; f < B_ * C_; f += 1024) {
        int b = f / C_, oc = f - b * C_;
        float a = 0.f;
        for (int s = 0; s < 8; ++s) a += gpart[((size_t)b * 8 + s) * C_ + oc];
        gs[f] = a;
    }
    __syncthreads();
    int j = t;
    float z[16];
    #pragma unroll
    for (int i = 0; i < 16; ++i) z[i] = b1[j];
    for (int c = 0; c < C_; ++c) {
        float w = w1[(size_t)c * PD_ + j];
        #pragma unroll
        for (int i = 0; i < 16; ++i) z[i] += gs[i * C_ + c] * w;
    }
    float mu = 0.f;
    #pragma unroll
    for (int i = 0; i < 16; ++i) mu += z[i];
    mu *= (1.0f / 16.0f);
    float var = 0.f;
    #pragma unroll
    for (int i = 0; i < 16; ++i) { float d = z[i] - mu; var += d * d; }
    var *= (1.0f / 16.0f);
    float sc = (1.0f / sqrtf(var + 1e-5f)) * gam[j];
    float bt = bet[j];
    #pragma unroll
    for (int i = 0; i < 16; ++i) {
        float zh = (z[i] - mu) * sc + bt;
        float ge = 0.5f * zh * (1.0f + erff(zh * 0.70710678118654752f));
        zs[i * PD_ + j] = ge;
    }
    __syncthreads();
    for (int idx = t; idx < B_ * NC_; idx += 1024) {
        int i = idx / NC_, jj = idx - i * NC_;
        float a = b2[jj];
        for (int k = 0; k < PD_; ++k) a += zs[i * PD_ + k] * w2[(size_t)k * NC_ + jj];
        pred[idx] = a;
    }
}

extern "C" void kernel_launch(void* const* d_in, const int* in_sizes, int n_in,
                              void* d_out, int out_size, void* d_ws, size_t ws_size,
                              hipStream_t stream) {
    const float* img    = (const float*)d_in[0];
    const float* conv_w = (const float*)d_in[1];
    const float* conv_b = (const float*)d_in[2];
    const float* gnn_w  = (const float*)d_in[3];
    const float* gnn_b  = (const float*)d_in[4];
    const float* w1     = (const float*)d_in[5];
    const float* b1     = (const float*)d_in[6];
    const float* bng    = (const float*)d_in[7];
    const float* bnb    = (const float*)d_in[8];
    const float* w2     = (const float*)d_in[9];
    const float* b2     = (const float*)d_in[10];
    float* out = (float*)d_out;

    float* XN = (float*)d_ws;                                   // BN*192 f32
    unsigned short* XS = (unsigned short*)(XN + (size_t)BN_ * C_); // BN*384 bf16
    float* Hh = (float*)XS;                                     // reuse after simmfma
    float* TOPV = (float*)(XS + (size_t)BN_ * 384);             // 2*BN*12
    int*   TOPI = (int*)(TOPV + (size_t)2 * BN_ * 12);          // 2*BN*12
    int*   NBR12 = TOPI + (size_t)2 * BN_ * 12;                 // BN*12
    int*   NBR9  = NBR12 + (size_t)BN_ * 12;                    // BN*9
    float* GPART = (float*)(NBR9 + (size_t)BN_ * K_);           // 128*C
    float* HOUT = XN;                                           // reuse after gnn

    (void)hipFuncSetAttribute((const void*)k_simmfma,
            hipFuncAttributeMaxDynamicSharedMemorySize, SIM_LDS);

    k_normalize<<<784, 256, 0, stream>>>(img, XN);
    k_patch   <<<1225, 256, 0, stream>>>(img, conv_w, conv_b, out + OUT_PP);
    k_split   <<<9408, 256, 0, stream>>>(XN, XS);
    k_simmfma <<<800, 256, SIM_LDS, stream>>>(XS, TOPV, TOPI);
    k_merge2  <<<196, 256, 0, stream>>>(TOPV, TOPI, NBR12);
    k_rescore <<<3136, 256, 0, stream>>>(XN, NBR12, NBR9);
    k_gnn     <<<1568, 192, 0, stream>>>(XN, gnn_w, gnn_b, Hh);
    k_edge    <<<12544, 256, 0, stream>>>(Hh, NBR9, out + OUT_EATT, HOUT);
    k_gred    <<<128, 192, 0, stream>>>(HOUT, GPART);
    k_mlp     <<<1, 1024, 0, stream>>>(GPART, w1, b1, bng, bnb, w2, b2, out);
}

// Round 3
// 780.795 us; speedup vs baseline: 5.1159x; 1.8079x over previous
//
#include <hip/hip_runtime.h>
#include <math.h>

#define B_  16
#define C_  192
#define N_  3136
#define BN_ 50176
#define K_  9
#define NC_ 100
#define PD_ 1024

#define OUT_EATT 1600
#define OUT_PP   453184

typedef short bf16x8 __attribute__((ext_vector_type(8)));
typedef float f32x16 __attribute__((ext_vector_type(16)));

// sorted-desc insertion, strict > (stable: earliest inserted wins ties)
template<int NL>
__device__ inline void ins_gt(float (&lv)[NL], int (&li)[NL], float v, int vi) {
    #pragma unroll
    for (int k = 0; k < NL; ++k) {
        bool p = v > lv[k];
        float fv = p ? lv[k] : v; int fi = p ? li[k] : vi;
        lv[k] = p ? v : lv[k];    li[k] = p ? vi : li[k];
        v = fv; vi = fi;
    }
}
// lexicographic (val desc, idx asc) insertion for merges
template<int NL>
__device__ inline void ins_lex(float (&lv)[NL], int (&li)[NL], float v, int vi) {
    if (v > lv[NL-1] || (v == lv[NL-1] && vi < li[NL-1])) {
        #pragma unroll
        for (int k = 0; k < NL; ++k) {
            bool p = (v > lv[k]) || (v == lv[k] && vi < li[k]);
            float fv = p ? lv[k] : v; int fi = p ? li[k] : vi;
            lv[k] = p ? v : lv[k];    li[k] = p ? vi : li[k];
            v = fv; vi = fi;
        }
    }
}

__device__ inline unsigned int bf16_rne(unsigned int u) {
    return (u + 0x7fffu + ((u >> 16) & 1u)) & 0xffff0000u;
}

// ---------------- normalize: [B,C,N] -> XN f32, XS bf16 hi|lo split, NORMS ----
__global__ __launch_bounds__(256) void k_normalize(const float* __restrict__ in,
        float* __restrict__ xn, unsigned short* __restrict__ xsn,
        float* __restrict__ norms) {
    __shared__ float tile[C_][65];
    __shared__ float part[4][64];
    __shared__ float rnorm_s[64];
    int blk = blockIdx.x;
    int b = blk / 49;
    int n0 = (blk % 49) * 64;
    int t = threadIdx.x;
    for (int f = t; f < C_ * 64; f += 256) {
        int c = f >> 6, n = f & 63;
        tile[c][n] = in[((size_t)b * C_ + c) * N_ + n0 + n];
    }
    __syncthreads();
    {
        int n = t & 63, qq = t >> 6;
        float s = 0.f;
        #pragma unroll
        for (int i = 0; i < 48; ++i) { float v = tile[qq * 48 + i][n]; s += v * v; }
        part[qq][n] = s;
    }
    __syncthreads();
    if (t < 64) {
        float tot = part[0][t] + part[1][t] + part[2][t] + part[3][t];
        float nrm = fmaxf(sqrtf(tot), 1e-12f);
        norms[(size_t)b * N_ + n0 + t] = nrm;
        rnorm_s[t] = 1.0f / nrm;
    }
    __syncthreads();
    for (int f = t; f < 64 * 96; f += 256) {
        int n = f / 96, cp = f - n * 96;
        int c = cp * 2;
        float r = rnorm_s[n];
        float v0 = tile[c][n] * r;
        float v1 = tile[c + 1][n] * r;
        size_t row = (size_t)b * N_ + n0 + n;
        *(float2*)(xn + row * C_ + c) = make_float2(v0, v1);
        unsigned int h0 = bf16_rne(__float_as_uint(v0));
        unsigned int h1 = bf16_rne(__float_as_uint(v1));
        unsigned int l0 = bf16_rne(__float_as_uint(v0 - __uint_as_float(h0)));
        unsigned int l1 = bf16_rne(__float_as_uint(v1 - __uint_as_float(h1)));
        unsigned int* xr = (unsigned int*)(xsn + row * 384);
        xr[cp]      = (h0 >> 16) | (h1 & 0xffff0000u);
        xr[96 + cp] = (l0 >> 16) | (l1 & 0xffff0000u);
    }
}

// ---------------- split conv_w / gnn_w into bf16 hi|lo layouts ----------------
// WSC[k][0..191]=hi(cw[k][c]), [192..383]=lo (k padded to 128 with zeros)
// WSG[j][0..191]=hi(gw[c][j]), [192..383]=lo
__global__ __launch_bounds__(256) void k_wsplit(const float* __restrict__ cw,
        const float* __restrict__ gw, unsigned short* __restrict__ wsc,
        unsigned short* __restrict__ wsg) {
    int id = blockIdx.x * 256 + threadIdx.x;   // 240*256 = 61440
    if (id < 128 * 192) {
        int k = id / 192, c = id - k * 192;
        float v = (k < 100) ? cw[k * 192 + c] : 0.f;
        unsigned int h = bf16_rne(__float_as_uint(v));
        wsc[(size_t)k * 384 + c] = (unsigned short)(h >> 16);
        wsc[(size_t)k * 384 + 192 + c] =
            (unsigned short)(bf16_rne(__float_as_uint(v - __uint_as_float(h))) >> 16);
    } else {
        int e = id - 128 * 192;
        int cc = e / 192, j = e - cc * 192;
        float v = gw[cc * 192 + j];
        unsigned int h = bf16_rne(__float_as_uint(v));
        wsg[(size_t)j * 384 + cc] = (unsigned short)(h >> 16);
        wsg[(size_t)j * 384 + 192 + cc] =
            (unsigned short)(bf16_rne(__float_as_uint(v - __uint_as_float(h))) >> 16);
    }
}

// stage one 32-col chunk (24KB) via global_load_lds; NLW = glds per wave
#define STAGE32(DST, SRCBASE, NLW) { \
    const char* s_ = (SRCBASE); \
    _Pragma("unroll") \
    for (int q_ = 0; q_ < NLW; ++q_) \
        __builtin_amdgcn_global_load_lds( \
            (const __attribute__((address_space(1))) unsigned int*)(s_ + q_ * 32), \
            (__attribute__((address_space(3))) unsigned int*)((DST) + (w * NLW + q_) * 1024), 16, 0, 0); }

// ---------------- MFMA sim + fused in-register top-12 ----------------
// grid 800: img(16) x rowblk(25) x half(2). 256 thr = 4 waves x 32 rows.
// swapped operands: D = cols x rows -> each lane owns one row's 16 cols in regs.
__global__ __launch_bounds__(256, 3) void k_simmfma(const unsigned short* __restrict__ xs,
        float* __restrict__ topv, int* __restrict__ topi) {
    __shared__ __align__(1024) char SMEM[49152];
    int bid = blockIdx.x;
    int img = bid & 15;
    int rest = bid >> 4;
    int rb = rest >> 1;
    int half = rest & 1;
    int t = threadIdx.x;
    int w = t >> 6, lane = t & 63;
    int l31 = lane & 31, lh = lane >> 5;
    const char* xsi = (const char*)(xs + (size_t)img * N_ * 384);

    int r = rb * 128 + w * 32 + l31;
    bool valid = r < N_;
    int rl = valid ? r : (N_ - 1);
    bf16x8 bfrag[24];
    {
        const char* rp = xsi + (size_t)rl * 768 + lh * 16;
        #pragma unroll
        for (int ks = 0; ks < 24; ++ks)
            bfrag[ks] = *(const bf16x8*)(rp + ks * 32);
    }
    float lv[12]; int li[12];
    #pragma unroll
    for (int k = 0; k < 12; ++k) { lv[k] = -1e30f; li[k] = 0; }

    int cbase = half * 1568;
    STAGE32(SMEM, xsi + (size_t)(cbase + l31) * 768 + w * 192 + lh * 16, 6);
    __syncthreads();

    for (int c = 0; c < 49; ++c) {
        char* cur = SMEM + (c & 1) * 24576;
        if (c < 48) {
            char* dst = SMEM + ((c & 1) ^ 1) * 24576;
            STAGE32(dst, xsi + (size_t)(cbase + (c + 1) * 32 + l31) * 768 + w * 192 + lh * 16, 6);
        }
        f32x16 acc;
        #pragma unroll
        for (int i = 0; i < 16; ++i) acc[i] = 0.f;
        const char* rp = cur + lh * 512 + l31 * 16;
        #pragma unroll
        for (int ks = 0; ks < 24; ++ks) {
            bf16x8 af = *(const bf16x8*)(rp + ks * 1024);
            acc = __builtin_amdgcn_mfma_f32_32x32x16_bf16(af, bfrag[ks], acc, 0, 0, 0);
        }
        if (valid) {
            int c0 = cbase + c * 32 + 4 * lh;
            #pragma unroll
            for (int g = 0; g < 4; ++g) {
                #pragma unroll
                for (int q = 0; q < 4; ++q) {
                    int cg = c0 + 8 * g + q;
                    float v = acc[4 * g + q];
                    if (cg != r && v > lv[11]) ins_gt<12>(lv, li, v, cg);
                }
            }
        }
        __syncthreads();
    }
    // merge partner lane (lane ^ 32 holds same row's other 16-col comb)
    float mv[12]; int mi[12];
    #pragma unroll
    for (int k = 0; k < 12; ++k) {
        mv[k] = __shfl_xor(lv[k], 32, 64);
        mi[k] = __shfl_xor(li[k], 32, 64);
    }
    #pragma unroll
    for (int k = 0; k < 12; ++k) ins_lex<12>(lv, li, mv[k], mi[k]);
    if (valid && lh == 0) {
        size_t base = ((size_t)half * BN_ + (size_t)img * N_ + r) * 12;
        #pragma unroll
        for (int k = 0; k < 12; ++k) { topv[base + k] = lv[k]; topi[base + k] = li[k]; }
    }
}

// ---------------- patch head via MFMA: out = norm[n] * (W @ xn^T) + b --------
// grid 784: img(16) x nsplit(49). 4 waves x 32 ch = 128 ch; 2 n-chunks of 32.
__global__ __launch_bounds__(256, 3) void k_patchmfma(const unsigned short* __restrict__ xs,
        const unsigned short* __restrict__ wsc, const float* __restrict__ norms,
        const float* __restrict__ cb, float* __restrict__ outp) {
    __shared__ __align__(1024) char SMEM[49152];
    int bid = blockIdx.x;
    int img = bid & 15;
    int n0 = (bid >> 4) * 64;
    int t = threadIdx.x;
    int w = t >> 6, lane = t & 63;
    int l31 = lane & 31, lh = lane >> 5;
    const char* xsi = (const char*)(xs + (size_t)img * N_ * 384);
    int ch = w * 32 + l31;
    bf16x8 bfrag[24];
    {
        const char* wp = (const char*)wsc + (size_t)ch * 768 + lh * 16;
        #pragma unroll
        for (int ks = 0; ks < 24; ++ks)
            bfrag[ks] = *(const bf16x8*)(wp + ks * 32);
    }
    float bias = (ch < NC_) ? cb[ch] : 0.f;
    STAGE32(SMEM, xsi + (size_t)(n0 + l31) * 768 + w * 192 + lh * 16, 6);
    __syncthreads();
    for (int c = 0; c < 2; ++c) {
        char* cur = SMEM + (c & 1) * 24576;
        if (c == 0)
            STAGE32(SMEM + 24576, xsi + (size_t)(n0 + 32 + l31) * 768 + w * 192 + lh * 16, 6);
        f32x16 acc;
        #pragma unroll
        for (int i = 0; i < 16; ++i) acc[i] = 0.f;
        const char* rp = cur + lh * 512 + l31 * 16;
        #pragma unroll
        for (int ks = 0; ks < 24; ++ks) {
            bf16x8 af = *(const bf16x8*)(rp + ks * 1024);
            acc = __builtin_amdgcn_mfma_f32_32x32x16_bf16(af, bfrag[ks], acc, 0, 0, 0);
        }
        if (ch < NC_) {
            int nb = n0 + c * 32 + 4 * lh;
            float* op = outp + ((size_t)(img * NC_ + ch)) * N_ + nb;
            const float* npv = norms + (size_t)img * N_ + nb;
            #pragma unroll
            for (int g = 0; g < 4; ++g) {
                float4 nv = *(const float4*)(npv + 8 * g);
                float4 o;
                o.x = acc[4 * g + 0] * nv.x + bias;
                o.y = acc[4 * g + 1] * nv.y + bias;
                o.z = acc[4 * g + 2] * nv.z + bias;
                o.w = acc[4 * g + 3] * nv.w + bias;
                *(float4*)(op + 8 * g) = o;
            }
        }
        __syncthreads();
    }
}

// ---------------- GNN linear+relu via MFMA: h = relu(XS @ WSG^T + b) ---------
// grid 392: 128 nodes/block. 6 waves x 32 j = 192 j; 4 node-chunks of 32.
__global__ __launch_bounds__(384, 3) void k_gnnmfma(const unsigned short* __restrict__ xs,
        const unsigned short* __restrict__ wsg, const float* __restrict__ gbias,
        float* __restrict__ h) {
    __shared__ __align__(1024) char SMEM[49152];
    int n0 = blockIdx.x * 128;
    int t = threadIdx.x;
    int w = t / 64, lane = t & 63;
    int l31 = lane & 31, lh = lane >> 5;
    int j = w * 32 + l31;
    bf16x8 bfrag[24];
    {
        const char* wp = (const char*)wsg + (size_t)j * 768 + lh * 16;
        #pragma unroll
        for (int ks = 0; ks < 24; ++ks)
            bfrag[ks] = *(const bf16x8*)(wp + ks * 32);
    }
    float bj = gbias[j];
    STAGE32(SMEM, (const char*)xs + (size_t)(n0 + l31) * 768 + w * 128 + lh * 16, 4);
    __syncthreads();
    for (int c = 0; c < 4; ++c) {
        char* cur = SMEM + (c & 1) * 24576;
        if (c < 3) {
            char* dst = SMEM + ((c & 1) ^ 1) * 24576;
            STAGE32(dst, (const char*)xs + (size_t)(n0 + (c + 1) * 32 + l31) * 768 + w * 128 + lh * 16, 4);
        }
        f32x16 acc;
        #pragma unroll
        for (int i = 0; i < 16; ++i) acc[i] = 0.f;
        const char* rp = cur + lh * 512 + l31 * 16;
        #pragma unroll
        for (int ks = 0; ks < 24; ++ks) {
            bf16x8 af = *(const bf16x8*)(rp + ks * 1024);
            acc = __builtin_amdgcn_mfma_f32_32x32x16_bf16(af, bfrag[ks], acc, 0, 0, 0);
        }
        int nb = n0 + c * 32 + 4 * lh;
        #pragma unroll
        for (int g = 0; g < 4; ++g)
            #pragma unroll
            for (int q = 0; q < 4; ++q)
                h[(size_t)(nb + 8 * g + q) * C_ + j] = fmaxf(acc[4 * g + q] + bj, 0.f);
        __syncthreads();
    }
}

// ---------------- merge 2 col-half partials -> top-12 candidates --------------
__global__ __launch_bounds__(256) void k_merge2(const float* __restrict__ topv,
        const int* __restrict__ topi, int* __restrict__ nbr12) {
    int row = blockIdx.x * 256 + threadIdx.x;      // 50176
    float lv[12]; int li[12];
    #pragma unroll
    for (int k = 0; k < 12; ++k) { lv[k] = -1e30f; li[k] = 0x7fffffff; }
    #pragma unroll
    for (int h = 0; h < 2; ++h) {
        size_t base = ((size_t)h * BN_ + row) * 12;
        #pragma unroll
        for (int k = 0; k < 12; ++k)
            ins_lex<12>(lv, li, topv[base + k], topi[base + k]);
    }
    int gb = (row / N_) * N_;
    int* np = nbr12 + (size_t)row * 12;
    #pragma unroll
    for (int k = 0; k < 12; ++k) np[k] = gb + li[k];
}

// ---------------- exact fp32 rescore of 12 candidates -> final top-9 ----------
__global__ __launch_bounds__(256) void k_rescore(const float* __restrict__ xn,
        const int* __restrict__ nbr12, int* __restrict__ nbr9) {
    int gid = blockIdx.x * 256 + threadIdx.x;
    int lane = threadIdx.x & 63;
    int row = (gid >> 6) * 4 + (lane >> 4);        // 0..50175
    int c = lane & 15;
    int cand = nbr12[(size_t)row * 12 + (c < 12 ? c : 0)];
    const float4* xa = (const float4*)(xn + (size_t)row * C_);
    const float4* xb = (const float4*)(xn + (size_t)cand * C_);
    float dot = 0.f;
    #pragma unroll
    for (int k = 0; k < 48; ++k) {
        float4 p = xa[k], q = xb[k];
        dot += p.x*q.x + p.y*q.y + p.z*q.z + p.w*q.w;
    }
    float v = (c < 12 && cand != row) ? dot : -1e30f;
    float lv[9]; int li[9];
    #pragma unroll
    for (int k = 0; k < 9; ++k) { lv[k] = -1e30f; li[k] = 0x7fffffff; }
    int gbase = lane & 48;
    #pragma unroll
    for (int j = 0; j < 12; ++j) {
        float vj = __shfl(v, gbase + j, 64);
        int  ij = __shfl(cand, gbase + j, 64);
        ins_lex<9>(lv, li, vj, ij);
    }
    if (c == 0) {
        int* np = nbr9 + (size_t)row * 9;
        #pragma unroll
        for (int k = 0; k < 9; ++k) np[k] = li[k];
    }
}

// ---------------- edge attention + neighbor mean aggregation ------------------
__global__ __launch_bounds__(256) void k_edge(const float* __restrict__ h,
        const int* __restrict__ nbr, float* __restrict__ eatt,
        float* __restrict__ hout) {
    int node = blockIdx.x * 4 + (threadIdx.x >> 6);
    int lane = threadIdx.x & 63;
    const float* hc = h + (size_t)node * C_;
    float c0 = hc[lane], c1 = hc[lane + 64], c2 = hc[lane + 128];
    float m0 = 0.f, m1 = 0.f, m2 = 0.f;
    const int* np_ = nbr + (size_t)node * K_;
    float* ep = eatt + (size_t)node * K_;
    #pragma unroll
    for (int k = 0; k < K_; ++k) {
        int src = np_[k];
        const float* hs = h + (size_t)src * C_;
        float s0 = hs[lane], s1 = hs[lane + 64], s2 = hs[lane + 128];
        float d = c0 * s0 + c1 * s1 + c2 * s2;
        d += __shfl_xor(d, 1, 64);  d += __shfl_xor(d, 2, 64);
        d += __shfl_xor(d, 4, 64);  d += __shfl_xor(d, 8, 64);
        d += __shfl_xor(d, 16, 64); d += __shfl_xor(d, 32, 64);
        if (lane == 0) ep[k] = 1.0f / (1.0f + expf(-d));
        m0 += s0; m1 += s1; m2 += s2;
    }
    const float r9 = 1.0f / 9.0f;
    float* ho = hout + (size_t)node * C_;
    ho[lane]       = c0 + m0 * r9;
    ho[lane + 64]  = c1 + m1 * r9;
    ho[lane + 128] = c2 + m2 * r9;
}

// ---------------- global add pool (partial) ----------------
__global__ __launch_bounds__(192) void k_gred(const float* __restrict__ hout,
        float* __restrict__ gpart) {
    int b = blockIdx.x >> 3, s = blockIdx.x & 7;
    int oc = threadIdx.x;
    float acc = 0.f;
    for (int n = s * 392; n < (s + 1) * 392; ++n)
        acc += hout[((size_t)b * N_ + n) * C_ + oc];
    gpart[(size_t)blockIdx.x * C_ + oc] = acc;
}

// ---------------- MLP head ----------------
__global__ __launch_bounds__(1024) void k_mlp(const float* __restrict__ gpart,
        const float* __restrict__ w1, const float* __restrict__ b1,
        const float* __restrict__ gam, const float* __restrict__ bet,
        const float* __restrict__ w2, const float* __restrict__ b2,
        float* __restrict__ pred) {
    __shared__ float gs[B_ * C_];
    __shared__ float zs[B_ * PD_];
    int t = threadIdx.x;
    for (int f = t; f < B_ * C_; f += 1024) {
        int b = f / C_, oc = f - b * C_;
        float a = 0.f;
        for (int s = 0; s < 8; ++s) a += gpart[((size_t)b * 8 + s) * C_ + oc];
        gs[f] = a;
    }
    __syncthreads();
    int j = t;
    float z[16];
    #pragma unroll
    for (int i = 0; i < 16; ++i) z[i] = b1[j];
    for (int c = 0; c < C_; ++c) {
        float w = w1[(size_t)c * PD_ + j];
        #pragma unroll
        for (int i = 0; i < 16; ++i) z[i] += gs[i * C_ + c] * w;
    }
    float mu = 0.f;
    #pragma unroll
    for (int i = 0; i < 16; ++i) mu += z[i];
    mu *= (1.0f / 16.0f);
    float var = 0.f;
    #pragma unroll
    for (int i = 0; i < 16; ++i) { float d = z[i] - mu; var += d * d; }
    var *= (1.0f / 16.0f);
    float sc = (1.0f / sqrtf(var + 1e-5f)) * gam[j];
    float bt = bet[j];
    #pragma unroll
    for (int i = 0; i < 16; ++i) {
        float zh = (z[i] - mu) * sc + bt;
        float ge = 0.5f * zh * (1.0f + erff(zh * 0.70710678118654752f));
        zs[i * PD_ + j] = ge;
    }
    __syncthreads();
    for (int idx = t; idx < B_ * NC_; idx += 1024) {
        int i = idx / NC_, jj = idx - i * NC_;
        float a = b2[jj];
        for (int k = 0; k < PD_; ++k) a += zs[i * PD_ + k] * w2[(size_t)k * NC_ + jj];
        pred[idx] = a;
    }
}

extern "C" void kernel_launch(void* const* d_in, const int* in_sizes, int n_in,
                              void* d_out, int out_size, void* d_ws, size_t ws_size,
                              hipStream_t stream) {
    const float* img    = (const float*)d_in[0];
    const float* conv_w = (const float*)d_in[1];
    const float* conv_b = (const float*)d_in[2];
    const float* gnn_w  = (const float*)d_in[3];
    const float* gnn_b  = (const float*)d_in[4];
    const float* w1     = (const float*)d_in[5];
    const float* b1     = (const float*)d_in[6];
    const float* bng    = (const float*)d_in[7];
    const float* bnb    = (const float*)d_in[8];
    const float* w2     = (const float*)d_in[9];
    const float* b2     = (const float*)d_in[10];
    float* out = (float*)d_out;

    float* XN            = (float*)d_ws;                        // BN*192 f32
    unsigned short* XS   = (unsigned short*)(XN + (size_t)BN_ * C_);  // BN*384
    float* TOPV          = (float*)(XS + (size_t)BN_ * 384);    // 2*BN*12
    int*   TOPI          = (int*)(TOPV + (size_t)2 * BN_ * 12);
    int*   NBR12         = TOPI + (size_t)2 * BN_ * 12;
    int*   NBR9          = NBR12 + (size_t)BN_ * 12;
    float* NORMS         = (float*)(NBR9 + (size_t)BN_ * K_);   // BN
    unsigned short* WSC  = (unsigned short*)(NORMS + BN_);      // 128*384
    unsigned short* WSG  = WSC + (size_t)128 * 384;             // 192*384
    float* GPART         = (float*)(WSG + (size_t)192 * 384);   // 128*C
    float* Hh            = XN;          // reuse: XN dead after k_rescore
    float* HOUT          = (float*)XS;  // reuse: XS dead after k_gnnmfma

    k_normalize<<<784, 256, 0, stream>>>(img, XN, XS, NORMS);
    k_wsplit   <<<240, 256, 0, stream>>>(conv_w, gnn_w, WSC, WSG);
    k_patchmfma<<<784, 256, 0, stream>>>(XS, WSC, NORMS, conv_b, out + OUT_PP);
    k_simmfma  <<<800, 256, 0, stream>>>(XS, TOPV, TOPI);
    k_merge2   <<<196, 256, 0, stream>>>(TOPV, TOPI, NBR12);
    k_rescore  <<<3136, 256, 0, stream>>>(XN, NBR12, NBR9);
    k_gnnmfma  <<<392, 384, 0, stream>>>(XS, WSG, gnn_b, Hh);
    k_edge     <<<12544, 256, 0, stream>>>(Hh, NBR9, out + OUT_EATT, HOUT);
    k_gred     <<<128, 192, 0, stream>>>(HOUT, GPART);
    k_mlp      <<<1, 1024, 0, stream>>>(GPART, w1, b1, bng, bnb, w2, b2, out);
}